// Round 1
// baseline (343.925 us; speedup 1.0000x reference)
//
#include <hip/hip_runtime.h>
#include <hip/hip_bf16.h>

// Problem constants (PhiAttention: B=2,S=1024,HID=2560,H=32,D=80,ROT=32)
#define Bq 2
#define Sq 1024
#define Tq 2048
#define HIDq 2560
#define Hq 32
#define Dq 80
#define NQKV 7680   // 3*HID

typedef __bf16 bf16x8 __attribute__((ext_vector_type(8)));
typedef float f32x4 __attribute__((ext_vector_type(4)));
typedef unsigned short u16x8 __attribute__((ext_vector_type(8)));
using bf16 = __hip_bfloat16;

__device__ __forceinline__ void gload_lds16(const bf16* g, bf16* l) {
  __builtin_amdgcn_global_load_lds((const __attribute__((address_space(1))) void*)g,
                                   (__attribute__((address_space(3))) void*)l,
                                   16, 0, 0);
}

// ---------------- cast h (fp32 -> bf16) ----------------
__global__ __launch_bounds__(256) void cast_h_kernel(const float* __restrict__ h,
                                                     bf16* __restrict__ hb) {
  int i = (blockIdx.x * 256 + threadIdx.x) * 4;
  float4 v = *(const float4*)(h + i);
  bf16 tmp[4];
  tmp[0] = __float2bfloat16(v.x);
  tmp[1] = __float2bfloat16(v.y);
  tmp[2] = __float2bfloat16(v.z);
  tmp[3] = __float2bfloat16(v.w);
  *(ushort4*)(hb + i) = *(ushort4*)tmp;
}

// ---------------- concat qkv bias ----------------
__global__ __launch_bounds__(256) void bias_concat_kernel(const float* __restrict__ qb,
                                                          const float* __restrict__ kb,
                                                          const float* __restrict__ vb,
                                                          float* __restrict__ bqkv) {
  int i = blockIdx.x * 256 + threadIdx.x;
  if (i < HIDq) bqkv[i] = qb[i];
  else if (i < 2 * HIDq) bqkv[i] = kb[i - HIDq];
  else bqkv[i] = vb[i - 2 * HIDq];
}

// ---------------- transpose-cast weights: wt[n][k] = w[k][n], fp32->bf16 ----------------
// grid (80,80,4) block (32,8); z: 0=q_w 1=k_w 2=v_w 3=dense_w
__global__ __launch_bounds__(256) void wtrans_kernel(const float* __restrict__ qw,
                                                     const float* __restrict__ kw,
                                                     const float* __restrict__ vw,
                                                     const float* __restrict__ dw,
                                                     bf16* __restrict__ wqkvt,
                                                     bf16* __restrict__ wdt) {
  __shared__ float tile[32][33];
  const int z = blockIdx.z;
  const float* src = (z == 0) ? qw : (z == 1) ? kw : (z == 2) ? vw : dw;
  const int n0 = blockIdx.x * 32;  // src col  (dst row)
  const int k0 = blockIdx.y * 32;  // src row  (dst col)
  const int tx = threadIdx.x, ty = threadIdx.y;
#pragma unroll
  for (int r = 0; r < 4; r++)
    tile[ty + 8 * r][tx] = src[(size_t)(k0 + ty + 8 * r) * HIDq + n0 + tx];
  __syncthreads();
  bf16* dst = (z < 3) ? (wqkvt + (size_t)z * HIDq * HIDq) : wdt;
#pragma unroll
  for (int r = 0; r < 4; r++)
    dst[(size_t)(n0 + ty + 8 * r) * HIDq + k0 + tx] = __float2bfloat16(tile[tx][ty + 8 * r]);
}

// ---------------- GEMM: C[M][N] = A[M][K] @ Bt[N][K]^T + bias ----------------
// m97 structure: 128x128 tile, 4 waves (2x2 of 64x64), BK=32, global_load_lds w16.
template <bool OUT_BF16>
__global__ __launch_bounds__(256) void gemm_bt_kernel(const bf16* __restrict__ A,
                                                      const bf16* __restrict__ Bt,
                                                      const float* __restrict__ bias,
                                                      void* __restrict__ Cout,
                                                      int M, int N, int K) {
  __shared__ bf16 As[128 * 32];
  __shared__ bf16 Bs[128 * 32];
  const int tid = threadIdx.x;
  const int wave = tid >> 6;
  const int lane = tid & 63;
  const int m0 = blockIdx.y * 128;
  const int n0 = blockIdx.x * 128;
  const int wm = (wave >> 1) * 64;
  const int wn = (wave & 1) * 64;
  const int ln = lane & 15;
  const int lg = lane >> 4;

  f32x4 acc[4][4];
  const f32x4 zz = {0.f, 0.f, 0.f, 0.f};
#pragma unroll
  for (int i = 0; i < 4; i++)
#pragma unroll
    for (int j = 0; j < 4; j++) acc[i][j] = zz;

  const int srow = lane >> 2;        // 0..15 within the wave's 16-row chunk
  const int scol = (lane & 3) * 8;   // bf16 col offset (16B lane chunk)
  const bf16* a_src = A + (size_t)(m0 + wave * 16 + srow) * K + scol;
  const bf16* b_src = Bt + (size_t)(n0 + wave * 16 + srow) * K + scol;
  bf16* a_dst = As + wave * 16 * 32;  // HW adds lane*16B
  bf16* b_dst = Bs + wave * 16 * 32;
  const size_t half_src = (size_t)64 * K;
  const int half_dst = 64 * 32;

  for (int k0 = 0; k0 < K; k0 += 32) {
    gload_lds16(a_src + k0, a_dst);
    gload_lds16(a_src + k0 + half_src, a_dst + half_dst);
    gload_lds16(b_src + k0, b_dst);
    gload_lds16(b_src + k0 + half_src, b_dst + half_dst);
    __syncthreads();  // drains vmcnt (global_load_lds) + barrier
    bf16x8 af[4], bf[4];
#pragma unroll
    for (int m = 0; m < 4; m++) af[m] = *(const bf16x8*)&As[(wm + m * 16 + ln) * 32 + lg * 8];
#pragma unroll
    for (int n = 0; n < 4; n++) bf[n] = *(const bf16x8*)&Bs[(wn + n * 16 + ln) * 32 + lg * 8];
#pragma unroll
    for (int m = 0; m < 4; m++)
#pragma unroll
      for (int n = 0; n < 4; n++)
        acc[m][n] = __builtin_amdgcn_mfma_f32_16x16x32_bf16(af[m], bf[n], acc[m][n], 0, 0, 0);
    __syncthreads();  // all waves done reading before next stage overwrites
  }

#pragma unroll
  for (int n = 0; n < 4; n++) {
    const int col = n0 + wn + n * 16 + ln;
    const float bv = bias[col];
#pragma unroll
    for (int m = 0; m < 4; m++) {
      const int rowb = m0 + wm + m * 16 + lg * 4;
#pragma unroll
      for (int r = 0; r < 4; r++) {
        const float v = acc[m][n][r] + bv;
        if (OUT_BF16)
          ((bf16*)Cout)[(size_t)(rowb + r) * N + col] = __float2bfloat16(v);
        else
          ((float*)Cout)[(size_t)(rowb + r) * N + col] = v;
      }
    }
  }
}

// ---------------- RoPE on q and k (in-place, bf16) ----------------
__global__ __launch_bounds__(256) void rope_kernel(bf16* __restrict__ qkv,
                                                   const int* __restrict__ positions) {
  int tid = blockIdx.x * 256 + threadIdx.x;  // T*H*16
  int i = tid & 15;
  int h = (tid >> 4) & 31;
  int t = tid >> 9;
  float pos = (float)positions[t];
  float inv = powf(10000.0f, -(float)(2 * i) / 32.0f);
  float ang = pos * inv;
  float s, c;
  sincosf(ang, &s, &c);
  size_t base = (size_t)t * NQKV + h * Dq + i;
  {
    float x1 = __bfloat162float(qkv[base]);
    float x2 = __bfloat162float(qkv[base + 16]);
    qkv[base] = __float2bfloat16(x1 * c - x2 * s);
    qkv[base + 16] = __float2bfloat16(x2 * c + x1 * s);
  }
  base += HIDq;
  {
    float x1 = __bfloat162float(qkv[base]);
    float x2 = __bfloat162float(qkv[base + 16]);
    qkv[base] = __float2bfloat16(x1 * c - x2 * s);
    qkv[base + 16] = __float2bfloat16(x2 * c + x1 * s);
  }
}

// ---------------- V transpose: vT[b][hd][s] = v[b*S+s][hd] ----------------
// grid (80,32,2) block (32,8)
__global__ __launch_bounds__(256) void vtrans_kernel(const bf16* __restrict__ qkv,
                                                     bf16* __restrict__ vT) {
  __shared__ bf16 tile[32][33];
  const int b = blockIdx.z;
  const int c0 = blockIdx.x * 32;  // hd
  const int s0 = blockIdx.y * 32;  // s
  const int tx = threadIdx.x, ty = threadIdx.y;
#pragma unroll
  for (int r = 0; r < 4; r++)
    tile[ty + 8 * r][tx] = qkv[(size_t)(b * Sq + s0 + ty + 8 * r) * NQKV + 2 * HIDq + c0 + tx];
  __syncthreads();
#pragma unroll
  for (int r = 0; r < 4; r++)
    vT[(size_t)b * HIDq * Sq + (size_t)(c0 + ty + 8 * r) * Sq + s0 + tx] = tile[tx][ty + 8 * r];
}

// ---------------- causal flash attention ----------------
// grid (8, 32, 2) = (qtile, head, batch), 256 threads (4 waves x 32 q-rows each)
__global__ __launch_bounds__(256) void attn_kernel(const bf16* __restrict__ qkv,
                                                   const bf16* __restrict__ vT,
                                                   bf16* __restrict__ obuf) {
  const int qt = blockIdx.x;
  const int h = blockIdx.y;
  const int b = blockIdx.z;
  __shared__ bf16 Qs[128][96];
  __shared__ bf16 Ks[64][96];
  __shared__ bf16 Vt[80][64];
  __shared__ bf16 Ps[4][32][64];
  const int tid = threadIdx.x;
  const int wave = tid >> 6, lane = tid & 63;
  const int ln = lane & 15, lg = lane >> 4;

  // stage Q tile (128 x 96, cols 80..95 zero)
  const u16x8 zv = {0, 0, 0, 0, 0, 0, 0, 0};
  for (int idx = tid; idx < 128 * 12; idx += 256) {
    int rr = idx / 12, c8 = idx % 12;
    u16x8 val = zv;
    if (c8 < 10)
      val = *(const u16x8*)(qkv + (size_t)(b * Sq + qt * 128 + rr) * NQKV + h * Dq + c8 * 8);
    *(u16x8*)&Qs[rr][c8 * 8] = val;
  }

  float mstate[2][4], lstate[2][4];
  f32x4 oacc[2][5];
  const f32x4 zz = {0.f, 0.f, 0.f, 0.f};
#pragma unroll
  for (int m = 0; m < 2; m++) {
#pragma unroll
    for (int r = 0; r < 4; r++) { mstate[m][r] = -__builtin_inff(); lstate[m][r] = 0.f; }
#pragma unroll
    for (int n = 0; n < 5; n++) oacc[m][n] = zz;
  }
  const float scale = 0.1118033988749895f;  // 1/sqrt(80)

  const int nkv = 2 * qt + 2;
  for (int j = 0; j < nkv; j++) {
    const int kv0 = j * 64;
    __syncthreads();  // previous iteration done reading Ks/Vt
    // stage K tile (64 x 96, padded)
    for (int idx = tid; idx < 64 * 12; idx += 256) {
      int rr = idx / 12, c8 = idx % 12;
      u16x8 val = zv;
      if (c8 < 10)
        val = *(const u16x8*)(qkv + (size_t)(b * Sq + kv0 + rr) * NQKV + HIDq + h * Dq + c8 * 8);
      *(u16x8*)&Ks[rr][c8 * 8] = val;
    }
    // stage Vt tile (80 x 64) from pre-transposed vT — contiguous rows
    for (int idx = tid; idx < 80 * 8; idx += 256) {
      int rr = idx / 8, c8 = idx % 8;
      *(u16x8*)&Vt[rr][c8 * 8] =
          *(const u16x8*)(vT + (size_t)b * HIDq * Sq + (size_t)(h * Dq + rr) * Sq + kv0 + c8 * 8);
    }
    __syncthreads();

    // QK^T : per wave 32 q-rows x 64 kv
    f32x4 sacc[2][4];
#pragma unroll
    for (int m = 0; m < 2; m++)
#pragma unroll
      for (int n = 0; n < 4; n++) sacc[m][n] = zz;
#pragma unroll
    for (int kc = 0; kc < 3; kc++) {
      bf16x8 aq[2], bk[4];
#pragma unroll
      for (int m = 0; m < 2; m++) aq[m] = *(const bf16x8*)&Qs[wave * 32 + m * 16 + ln][kc * 32 + lg * 8];
#pragma unroll
      for (int n = 0; n < 4; n++) bk[n] = *(const bf16x8*)&Ks[n * 16 + ln][kc * 32 + lg * 8];
#pragma unroll
      for (int m = 0; m < 2; m++)
#pragma unroll
        for (int n = 0; n < 4; n++)
          sacc[m][n] = __builtin_amdgcn_mfma_f32_16x16x32_bf16(aq[m], bk[n], sacc[m][n], 0, 0, 0);
    }

    // online softmax (rows owned per-lane-group; reduce across 16 lanes)
#pragma unroll
    for (int m = 0; m < 2; m++) {
#pragma unroll
      for (int r = 0; r < 4; r++) {
        const int rloc = wave * 32 + m * 16 + lg * 4 + r;
        const int qg = qt * 128 + rloc;
        float v[4];
        float vmax = -__builtin_inff();
#pragma unroll
        for (int n = 0; n < 4; n++) {
          const int kg = kv0 + n * 16 + ln;
          float x = sacc[m][n][r] * scale;
          if (kg > qg) x = -__builtin_inff();
          v[n] = x;
          vmax = fmaxf(vmax, x);
        }
#pragma unroll
        for (int off = 8; off >= 1; off >>= 1) vmax = fmaxf(vmax, __shfl_xor(vmax, off, 64));
        const float mo = mstate[m][r];
        const float mn = fmaxf(mo, vmax);
        const float alpha = __expf(mo - mn);
        float psum = 0.f;
#pragma unroll
        for (int n = 0; n < 4; n++) {
          const float p = __expf(v[n] - mn);
          psum += p;
          Ps[wave][m * 16 + lg * 4 + r][n * 16 + ln] = __float2bfloat16(p);
        }
#pragma unroll
        for (int off = 8; off >= 1; off >>= 1) psum += __shfl_xor(psum, off, 64);
        lstate[m][r] = lstate[m][r] * alpha + psum;
        mstate[m][r] = mn;
#pragma unroll
        for (int n5 = 0; n5 < 5; n5++) oacc[m][n5][r] *= alpha;
      }
    }
    // ensure P LDS writes visible to cross-lane reads within the wave
    asm volatile("s_waitcnt lgkmcnt(0)" ::: "memory");
    __builtin_amdgcn_sched_barrier(0);

    // PV : oacc += P @ V
#pragma unroll
    for (int kc = 0; kc < 2; kc++) {
      bf16x8 ap[2], bv[5];
#pragma unroll
      for (int m = 0; m < 2; m++) ap[m] = *(const bf16x8*)&Ps[wave][m * 16 + ln][kc * 32 + lg * 8];
#pragma unroll
      for (int n = 0; n < 5; n++) bv[n] = *(const bf16x8*)&Vt[n * 16 + ln][kc * 32 + lg * 8];
#pragma unroll
      for (int m = 0; m < 2; m++)
#pragma unroll
        for (int n = 0; n < 5; n++)
          oacc[m][n] = __builtin_amdgcn_mfma_f32_16x16x32_bf16(ap[m], bv[n], oacc[m][n], 0, 0, 0);
    }
  }

  // epilogue: o = oacc / l  -> obuf[t][h*80+d]
#pragma unroll
  for (int m = 0; m < 2; m++) {
#pragma unroll
    for (int r = 0; r < 4; r++) {
      const int rloc = wave * 32 + m * 16 + lg * 4 + r;
      const float inv = 1.0f / lstate[m][r];
      const size_t rowbase = (size_t)(b * Sq + qt * 128 + rloc) * HIDq + h * Dq;
#pragma unroll
      for (int n5 = 0; n5 < 5; n5++)
        obuf[rowbase + n5 * 16 + ln] = __float2bfloat16(oacc[m][n5][r] * inv);
    }
  }
}

// ---------------- launch ----------------
extern "C" void kernel_launch(void* const* d_in, const int* in_sizes, int n_in,
                              void* d_out, int out_size, void* d_ws, size_t ws_size,
                              hipStream_t stream) {
  const float* h = (const float*)d_in[0];
  const float* q_w = (const float*)d_in[3];
  const float* q_b = (const float*)d_in[4];
  const float* k_w = (const float*)d_in[5];
  const float* k_b = (const float*)d_in[6];
  const float* v_w = (const float*)d_in[7];
  const float* v_b = (const float*)d_in[8];
  const float* dw = (const float*)d_in[9];
  const float* db = (const float*)d_in[10];
  const int* positions = (const int*)d_in[11];

  // workspace layout (bytes); vT aliases hb (dead after QKV gemm),
  // obuf aliases wqkvt (dead after QKV gemm). All regions rewritten each call.
  if (ws_size < 94402560ull) return;
  char* ws = (char*)d_ws;
  bf16* hb = (bf16*)(ws);                    // 10,485,760
  bf16* wqkvt = (bf16*)(ws + 10485760);      // 39,321,600
  bf16* wdt = (bf16*)(ws + 49807360);        // 13,107,200
  bf16* qkv = (bf16*)(ws + 62914560);        // 31,457,280
  float* bqkv = (float*)(ws + 94371840);     // 30,720
  bf16* vT = hb;
  bf16* obuf = wqkvt;

  cast_h_kernel<<<5120, 256, 0, stream>>>(h, hb);
  bias_concat_kernel<<<30, 256, 0, stream>>>(q_b, k_b, v_b, bqkv);
  wtrans_kernel<<<dim3(80, 80, 4), dim3(32, 8), 0, stream>>>(q_w, k_w, v_w, dw, wqkvt, wdt);
  gemm_bt_kernel<true><<<dim3(60, 16), 256, 0, stream>>>(hb, wqkvt, bqkv, qkv, Tq, NQKV, HIDq);
  rope_kernel<<<4096, 256, 0, stream>>>(qkv, positions);
  vtrans_kernel<<<dim3(80, 32, 2), dim3(32, 8), 0, stream>>>(qkv, vT);
  attn_kernel<<<dim3(8, 32, 2), 256, 0, stream>>>(qkv, vT, obuf);
  gemm_bt_kernel<false><<<dim3(20, 16), 256, 0, stream>>>(obuf, wdt, db, d_out, Tq, HIDq, HIDq);
}

// Round 2
// 294.984 us; speedup vs baseline: 1.1659x; 1.1659x over previous
//
#include <hip/hip_runtime.h>
#include <hip/hip_bf16.h>

// Problem constants (PhiAttention: B=2,S=1024,HID=2560,H=32,D=80,ROT=32)
#define Bq 2
#define Sq 1024
#define Tq 2048
#define HIDq 2560
#define Hq 32
#define Dq 80
#define NQKV 7680   // 3*HID

typedef __bf16 bf16x8 __attribute__((ext_vector_type(8)));
typedef float f32x4 __attribute__((ext_vector_type(4)));
typedef unsigned short u16x8 __attribute__((ext_vector_type(8)));
using bf16 = __hip_bfloat16;

__device__ __forceinline__ void gload_lds16(const bf16* g, bf16* l) {
  __builtin_amdgcn_global_load_lds((const __attribute__((address_space(1))) void*)g,
                                   (__attribute__((address_space(3))) void*)l,
                                   16, 0, 0);
}

// ---------------- cast h (fp32 -> bf16) ----------------
__global__ __launch_bounds__(256) void cast_h_kernel(const float* __restrict__ h,
                                                     bf16* __restrict__ hb) {
  int i = (blockIdx.x * 256 + threadIdx.x) * 4;
  float4 v = *(const float4*)(h + i);
  bf16 tmp[4];
  tmp[0] = __float2bfloat16(v.x);
  tmp[1] = __float2bfloat16(v.y);
  tmp[2] = __float2bfloat16(v.z);
  tmp[3] = __float2bfloat16(v.w);
  *(ushort4*)(hb + i) = *(ushort4*)tmp;
}

// ---------------- concat qkv bias ----------------
__global__ __launch_bounds__(256) void bias_concat_kernel(const float* __restrict__ qb,
                                                          const float* __restrict__ kb,
                                                          const float* __restrict__ vb,
                                                          float* __restrict__ bqkv) {
  int i = blockIdx.x * 256 + threadIdx.x;
  if (i < HIDq) bqkv[i] = qb[i];
  else if (i < 2 * HIDq) bqkv[i] = kb[i - HIDq];
  else bqkv[i] = vb[i - 2 * HIDq];
}

// ---------------- transpose-cast weights: wt[n][k] = w[k][n], fp32->bf16 ----------------
// grid (80,80,4) block (32,8); z: 0=q_w 1=k_w 2=v_w 3=dense_w
__global__ __launch_bounds__(256) void wtrans_kernel(const float* __restrict__ qw,
                                                     const float* __restrict__ kw,
                                                     const float* __restrict__ vw,
                                                     const float* __restrict__ dw,
                                                     bf16* __restrict__ wqkvt,
                                                     bf16* __restrict__ wdt) {
  __shared__ float tile[32][33];
  const int z = blockIdx.z;
  const float* src = (z == 0) ? qw : (z == 1) ? kw : (z == 2) ? vw : dw;
  const int n0 = blockIdx.x * 32;  // src col  (dst row)
  const int k0 = blockIdx.y * 32;  // src row  (dst col)
  const int tx = threadIdx.x, ty = threadIdx.y;
#pragma unroll
  for (int r = 0; r < 4; r++)
    tile[ty + 8 * r][tx] = src[(size_t)(k0 + ty + 8 * r) * HIDq + n0 + tx];
  __syncthreads();
  bf16* dst = (z < 3) ? (wqkvt + (size_t)z * HIDq * HIDq) : wdt;
#pragma unroll
  for (int r = 0; r < 4; r++)
    dst[(size_t)(n0 + ty + 8 * r) * HIDq + k0 + tx] = __float2bfloat16(tile[tx][ty + 8 * r]);
}

// ================= 256x256-tile pipelined GEMM (T1+T2+T3/T4+T5) =================
// C[M][N] = A[M][K] @ Bt[N][K]^T + bias.  8 waves (2Mx4N), per-wave C = 128x64.
// BK=32, 3-buffer LDS ring (96 KB), counted vmcnt(4), raw s_barrier, XOR swizzle.
//
// LDS swizzle bijection (within a 256-row x 32-col bf16 panel, 64 B rows):
//   off(row,col2) = ((row ^ ((row>>2)&1)) << 6) | (col2 ^ ((row&3)<<4))
// Staging writes linearly (global_load_lds), so the global SOURCE address is
// pre-permuted with the inverse (same involution); ds_read applies it on read.
template <bool OUT_BF16>
__global__ __launch_bounds__(512, 2) void gemm256_kernel(const bf16* __restrict__ A,
                                                         const bf16* __restrict__ Bt,
                                                         const float* __restrict__ bias,
                                                         void* __restrict__ Cout,
                                                         int M, int N, int K, int tM) {
  __shared__ char smem[3 * 32768];  // 3 x (A 16KB + B 16KB)
  const int tid = threadIdx.x;
  const int lane = tid & 63;
  const int ln = lane & 15, lg = lane >> 4;
  const int wave = tid >> 6;
  const int wm = wave >> 2;   // 0..1
  const int wn = wave & 3;    // 0..3

  // XCD-aware bijective block swizzle (grid % 8 == 0 for our launches)
  int bid = blockIdx.x;
  int swz = bid;
  int nwg = gridDim.x;
  if ((nwg & 7) == 0) { int cpx = nwg >> 3; swz = (bid & 7) * cpx + (bid >> 3); }
  const int m0 = (swz % tM) * 256;
  const int n0 = (swz / tM) * 256;

  const int NT = K >> 5;  // K / 32

  f32x4 acc[8][4];
  const f32x4 zz = {0.f, 0.f, 0.f, 0.f};
#pragma unroll
  for (int i = 0; i < 8; ++i)
#pragma unroll
    for (int j = 0; j < 4; ++j) acc[i][j] = zz;

  // --- staging: 4 global_load_lds calls per K-tile (A 16KB + B 16KB) ---
  const int Rl0 = tid >> 2;        // stored-row within an 8KB call (0..127)
  const int slot = tid & 3;        // 16B slot within the 64B row
  const int wbase = (tid >> 6) * 1024;

  auto STAGE = [&](int t, int b) {
    const int k0 = t << 5;
    char* Ab = smem + b * 32768;
    char* Bb = Ab + 16384;
#pragma unroll
    for (int c = 0; c < 2; ++c) {
      const int srow = c * 128 + Rl0;
      const int row = srow ^ ((srow >> 2) & 1);   // involution (bit0 ^= bit2)
      const int col8 = slot ^ (row & 3);          // inverse col swizzle
      gload_lds16(A + (size_t)(m0 + row) * K + k0 + col8 * 8,
                  (bf16*)(Ab + c * 8192 + wbase));
      gload_lds16(Bt + (size_t)(n0 + row) * K + k0 + col8 * 8,
                  (bf16*)(Bb + c * 8192 + wbase));
    }
  };

  // swizzled fragment read: logical (row, k-slot lg) -> byte offset
  auto FRAG = [&](const char* base, int row) -> bf16x8 {
    const unsigned off = ((unsigned)((row ^ ((row >> 2) & 1)) << 6)) |
                         (((unsigned)lg << 4) ^ ((unsigned)(row & 3) << 4));
    return *(const bf16x8*)(base + off);
  };

  // prologue: 2 tiles in flight
  STAGE(0, 0);
  STAGE(1, 1);
  asm volatile("s_waitcnt vmcnt(4)" ::: "memory");  // tile 0 landed
  __builtin_amdgcn_s_barrier();

  for (int t = 0; t < NT; ++t) {
    const int cb = t % 3;
    const char* Ab = smem + cb * 32768;
    const char* Bb = Ab + 16384;
    if (t + 2 < NT) STAGE(t + 2, (t + 2) % 3);

    // phase A: mi 0..3
    bf16x8 af[4], bfr[4];
#pragma unroll
    for (int i = 0; i < 4; ++i) af[i] = FRAG(Ab, wm * 128 + i * 16 + ln);
#pragma unroll
    for (int j = 0; j < 4; ++j) bfr[j] = FRAG(Bb, wn * 64 + j * 16 + ln);
    __builtin_amdgcn_s_setprio(1);
#pragma unroll
    for (int i = 0; i < 4; ++i)
#pragma unroll
      for (int j = 0; j < 4; ++j)
        acc[i][j] = __builtin_amdgcn_mfma_f32_16x16x32_bf16(af[i], bfr[j], acc[i][j], 0, 0, 0);
    __builtin_amdgcn_s_setprio(0);

    // phase B: mi 4..7 (B fragments reused from registers)
    bf16x8 ag[4];
#pragma unroll
    for (int i = 0; i < 4; ++i) ag[i] = FRAG(Ab, wm * 128 + 64 + i * 16 + ln);
    __builtin_amdgcn_s_setprio(1);
#pragma unroll
    for (int i = 0; i < 4; ++i)
#pragma unroll
      for (int j = 0; j < 4; ++j)
        acc[4 + i][j] = __builtin_amdgcn_mfma_f32_16x16x32_bf16(ag[i], bfr[j], acc[4 + i][j], 0, 0, 0);
    __builtin_amdgcn_s_setprio(0);

    // tile boundary: ensure tile t+1 landed (counted — newest 4 may stay in flight)
    if (t + 2 < NT) asm volatile("s_waitcnt vmcnt(4)" ::: "memory");
    else            asm volatile("s_waitcnt vmcnt(0)" ::: "memory");
    __builtin_amdgcn_s_barrier();
  }

  // epilogue
#pragma unroll
  for (int j = 0; j < 4; ++j) {
    const int col = n0 + wn * 64 + j * 16 + ln;
    const float bv = bias[col];
#pragma unroll
    for (int i = 0; i < 8; ++i) {
      const int rowb = m0 + wm * 128 + i * 16 + lg * 4;
#pragma unroll
      for (int r = 0; r < 4; ++r) {
        const float v = acc[i][j][r] + bv;
        if (OUT_BF16)
          ((bf16*)Cout)[(size_t)(rowb + r) * N + col] = __float2bfloat16(v);
        else
          ((float*)Cout)[(size_t)(rowb + r) * N + col] = v;
      }
    }
  }
}

// ---------------- GEMM: C[M][N] = A[M][K] @ Bt[N][K]^T + bias (old 128x128) ----------------
template <bool OUT_BF16>
__global__ __launch_bounds__(256) void gemm_bt_kernel(const bf16* __restrict__ A,
                                                      const bf16* __restrict__ Bt,
                                                      const float* __restrict__ bias,
                                                      void* __restrict__ Cout,
                                                      int M, int N, int K) {
  __shared__ bf16 As[128 * 32];
  __shared__ bf16 Bs[128 * 32];
  const int tid = threadIdx.x;
  const int wave = tid >> 6;
  const int lane = tid & 63;
  const int m0 = blockIdx.y * 128;
  const int n0 = blockIdx.x * 128;
  const int wm = (wave >> 1) * 64;
  const int wn = (wave & 1) * 64;
  const int ln = lane & 15;
  const int lg = lane >> 4;

  f32x4 acc[4][4];
  const f32x4 zz = {0.f, 0.f, 0.f, 0.f};
#pragma unroll
  for (int i = 0; i < 4; i++)
#pragma unroll
    for (int j = 0; j < 4; j++) acc[i][j] = zz;

  const int srow = lane >> 2;
  const int scol = (lane & 3) * 8;
  const bf16* a_src = A + (size_t)(m0 + wave * 16 + srow) * K + scol;
  const bf16* b_src = Bt + (size_t)(n0 + wave * 16 + srow) * K + scol;
  bf16* a_dst = As + wave * 16 * 32;
  bf16* b_dst = Bs + wave * 16 * 32;
  const size_t half_src = (size_t)64 * K;
  const int half_dst = 64 * 32;

  for (int k0 = 0; k0 < K; k0 += 32) {
    gload_lds16(a_src + k0, a_dst);
    gload_lds16(a_src + k0 + half_src, a_dst + half_dst);
    gload_lds16(b_src + k0, b_dst);
    gload_lds16(b_src + k0 + half_src, b_dst + half_dst);
    __syncthreads();
    bf16x8 af[4], bf[4];
#pragma unroll
    for (int m = 0; m < 4; m++) af[m] = *(const bf16x8*)&As[(wm + m * 16 + ln) * 32 + lg * 8];
#pragma unroll
    for (int n = 0; n < 4; n++) bf[n] = *(const bf16x8*)&Bs[(wn + n * 16 + ln) * 32 + lg * 8];
#pragma unroll
    for (int m = 0; m < 4; m++)
#pragma unroll
      for (int n = 0; n < 4; n++)
        acc[m][n] = __builtin_amdgcn_mfma_f32_16x16x32_bf16(af[m], bf[n], acc[m][n], 0, 0, 0);
    __syncthreads();
  }

#pragma unroll
  for (int n = 0; n < 4; n++) {
    const int col = n0 + wn + n * 16 + ln;
    const float bv = bias[col];
#pragma unroll
    for (int m = 0; m < 4; m++) {
      const int rowb = m0 + wm + m * 16 + lg * 4;
#pragma unroll
      for (int r = 0; r < 4; r++) {
        const float v = acc[m][n][r] + bv;
        if (OUT_BF16)
          ((bf16*)Cout)[(size_t)(rowb + r) * N + col] = __float2bfloat16(v);
        else
          ((float*)Cout)[(size_t)(rowb + r) * N + col] = v;
      }
    }
  }
}

// ---------------- RoPE on q and k (in-place, bf16) ----------------
__global__ __launch_bounds__(256) void rope_kernel(bf16* __restrict__ qkv,
                                                   const int* __restrict__ positions) {
  int tid = blockIdx.x * 256 + threadIdx.x;  // T*H*16
  int i = tid & 15;
  int h = (tid >> 4) & 31;
  int t = tid >> 9;
  float pos = (float)positions[t];
  float inv = powf(10000.0f, -(float)(2 * i) / 32.0f);
  float ang = pos * inv;
  float s, c;
  sincosf(ang, &s, &c);
  size_t base = (size_t)t * NQKV + h * Dq + i;
  {
    float x1 = __bfloat162float(qkv[base]);
    float x2 = __bfloat162float(qkv[base + 16]);
    qkv[base] = __float2bfloat16(x1 * c - x2 * s);
    qkv[base + 16] = __float2bfloat16(x2 * c + x1 * s);
  }
  base += HIDq;
  {
    float x1 = __bfloat162float(qkv[base]);
    float x2 = __bfloat162float(qkv[base + 16]);
    qkv[base] = __float2bfloat16(x1 * c - x2 * s);
    qkv[base + 16] = __float2bfloat16(x2 * c + x1 * s);
  }
}

// ---------------- V transpose: vT[b][hd][s] = v[b*S+s][hd] ----------------
__global__ __launch_bounds__(256) void vtrans_kernel(const bf16* __restrict__ qkv,
                                                     bf16* __restrict__ vT) {
  __shared__ bf16 tile[32][33];
  const int b = blockIdx.z;
  const int c0 = blockIdx.x * 32;  // hd
  const int s0 = blockIdx.y * 32;  // s
  const int tx = threadIdx.x, ty = threadIdx.y;
#pragma unroll
  for (int r = 0; r < 4; r++)
    tile[ty + 8 * r][tx] = qkv[(size_t)(b * Sq + s0 + ty + 8 * r) * NQKV + 2 * HIDq + c0 + tx];
  __syncthreads();
#pragma unroll
  for (int r = 0; r < 4; r++)
    vT[(size_t)b * HIDq * Sq + (size_t)(c0 + ty + 8 * r) * Sq + s0 + tx] = tile[tx][ty + 8 * r];
}

// ---------------- causal flash attention ----------------
// grid (8, 32, 2) = (qtile, head, batch), 256 threads (4 waves x 32 q-rows each)
__global__ __launch_bounds__(256) void attn_kernel(const bf16* __restrict__ qkv,
                                                   const bf16* __restrict__ vT,
                                                   bf16* __restrict__ obuf) {
  const int qt = blockIdx.x;
  const int h = blockIdx.y;
  const int b = blockIdx.z;
  __shared__ bf16 Qs[128][96];
  __shared__ bf16 Ks[64][96];
  __shared__ bf16 Vt[80][64];
  __shared__ bf16 Ps[4][32][64];
  const int tid = threadIdx.x;
  const int wave = tid >> 6, lane = tid & 63;
  const int ln = lane & 15, lg = lane >> 4;

  const u16x8 zv = {0, 0, 0, 0, 0, 0, 0, 0};
  for (int idx = tid; idx < 128 * 12; idx += 256) {
    int rr = idx / 12, c8 = idx % 12;
    u16x8 val = zv;
    if (c8 < 10)
      val = *(const u16x8*)(qkv + (size_t)(b * Sq + qt * 128 + rr) * NQKV + h * Dq + c8 * 8);
    *(u16x8*)&Qs[rr][c8 * 8] = val;
  }

  float mstate[2][4], lstate[2][4];
  f32x4 oacc[2][5];
  const f32x4 zz = {0.f, 0.f, 0.f, 0.f};
#pragma unroll
  for (int m = 0; m < 2; m++) {
#pragma unroll
    for (int r = 0; r < 4; r++) { mstate[m][r] = -__builtin_inff(); lstate[m][r] = 0.f; }
#pragma unroll
    for (int n = 0; n < 5; n++) oacc[m][n] = zz;
  }
  const float scale = 0.1118033988749895f;  // 1/sqrt(80)

  const int nkv = 2 * qt + 2;
  for (int j = 0; j < nkv; j++) {
    const int kv0 = j * 64;
    __syncthreads();
    for (int idx = tid; idx < 64 * 12; idx += 256) {
      int rr = idx / 12, c8 = idx % 12;
      u16x8 val = zv;
      if (c8 < 10)
        val = *(const u16x8*)(qkv + (size_t)(b * Sq + kv0 + rr) * NQKV + HIDq + h * Dq + c8 * 8);
      *(u16x8*)&Ks[rr][c8 * 8] = val;
    }
    for (int idx = tid; idx < 80 * 8; idx += 256) {
      int rr = idx / 8, c8 = idx % 8;
      *(u16x8*)&Vt[rr][c8 * 8] =
          *(const u16x8*)(vT + (size_t)b * HIDq * Sq + (size_t)(h * Dq + rr) * Sq + kv0 + c8 * 8);
    }
    __syncthreads();

    f32x4 sacc[2][4];
#pragma unroll
    for (int m = 0; m < 2; m++)
#pragma unroll
      for (int n = 0; n < 4; n++) sacc[m][n] = zz;
#pragma unroll
    for (int kc = 0; kc < 3; kc++) {
      bf16x8 aq[2], bk[4];
#pragma unroll
      for (int m = 0; m < 2; m++) aq[m] = *(const bf16x8*)&Qs[wave * 32 + m * 16 + ln][kc * 32 + lg * 8];
#pragma unroll
      for (int n = 0; n < 4; n++) bk[n] = *(const bf16x8*)&Ks[n * 16 + ln][kc * 32 + lg * 8];
#pragma unroll
      for (int m = 0; m < 2; m++)
#pragma unroll
        for (int n = 0; n < 4; n++)
          sacc[m][n] = __builtin_amdgcn_mfma_f32_16x16x32_bf16(aq[m], bk[n], sacc[m][n], 0, 0, 0);
    }

#pragma unroll
    for (int m = 0; m < 2; m++) {
#pragma unroll
      for (int r = 0; r < 4; r++) {
        const int rloc = wave * 32 + m * 16 + lg * 4 + r;
        const int qg = qt * 128 + rloc;
        float v[4];
        float vmax = -__builtin_inff();
#pragma unroll
        for (int n = 0; n < 4; n++) {
          const int kg = kv0 + n * 16 + ln;
          float x = sacc[m][n][r] * scale;
          if (kg > qg) x = -__builtin_inff();
          v[n] = x;
          vmax = fmaxf(vmax, x);
        }
#pragma unroll
        for (int off = 8; off >= 1; off >>= 1) vmax = fmaxf(vmax, __shfl_xor(vmax, off, 64));
        const float mo = mstate[m][r];
        const float mn = fmaxf(mo, vmax);
        const float alpha = __expf(mo - mn);
        float psum = 0.f;
#pragma unroll
        for (int n = 0; n < 4; n++) {
          const float p = __expf(v[n] - mn);
          psum += p;
          Ps[wave][m * 16 + lg * 4 + r][n * 16 + ln] = __float2bfloat16(p);
        }
#pragma unroll
        for (int off = 8; off >= 1; off >>= 1) psum += __shfl_xor(psum, off, 64);
        lstate[m][r] = lstate[m][r] * alpha + psum;
        mstate[m][r] = mn;
#pragma unroll
        for (int n5 = 0; n5 < 5; n5++) oacc[m][n5][r] *= alpha;
      }
    }
    asm volatile("s_waitcnt lgkmcnt(0)" ::: "memory");
    __builtin_amdgcn_sched_barrier(0);

#pragma unroll
    for (int kc = 0; kc < 2; kc++) {
      bf16x8 ap[2], bv[5];
#pragma unroll
      for (int m = 0; m < 2; m++) ap[m] = *(const bf16x8*)&Ps[wave][m * 16 + ln][kc * 32 + lg * 8];
#pragma unroll
      for (int n = 0; n < 5; n++) bv[n] = *(const bf16x8*)&Vt[n * 16 + ln][kc * 32 + lg * 8];
#pragma unroll
      for (int m = 0; m < 2; m++)
#pragma unroll
        for (int n = 0; n < 5; n++)
          oacc[m][n] = __builtin_amdgcn_mfma_f32_16x16x32_bf16(ap[m], bv[n], oacc[m][n], 0, 0, 0);
    }
  }

#pragma unroll
  for (int m = 0; m < 2; m++) {
#pragma unroll
    for (int r = 0; r < 4; r++) {
      const int rloc = wave * 32 + m * 16 + lg * 4 + r;
      const float inv = 1.0f / lstate[m][r];
      const size_t rowbase = (size_t)(b * Sq + qt * 128 + rloc) * HIDq + h * Dq;
#pragma unroll
      for (int n5 = 0; n5 < 5; n5++)
        obuf[rowbase + n5 * 16 + ln] = __float2bfloat16(oacc[m][n5][r] * inv);
    }
  }
}

// ---------------- launch ----------------
extern "C" void kernel_launch(void* const* d_in, const int* in_sizes, int n_in,
                              void* d_out, int out_size, void* d_ws, size_t ws_size,
                              hipStream_t stream) {
  const float* h = (const float*)d_in[0];
  const float* q_w = (const float*)d_in[3];
  const float* q_b = (const float*)d_in[4];
  const float* k_w = (const float*)d_in[5];
  const float* k_b = (const float*)d_in[6];
  const float* v_w = (const float*)d_in[7];
  const float* v_b = (const float*)d_in[8];
  const float* dw = (const float*)d_in[9];
  const float* db = (const float*)d_in[10];
  const int* positions = (const int*)d_in[11];

  if (ws_size < 94402560ull) return;
  char* ws = (char*)d_ws;
  bf16* hb = (bf16*)(ws);                    // 10,485,760
  bf16* wqkvt = (bf16*)(ws + 10485760);      // 39,321,600
  bf16* wdt = (bf16*)(ws + 49807360);        // 13,107,200
  bf16* qkv = (bf16*)(ws + 62914560);        // 31,457,280
  float* bqkv = (float*)(ws + 94371840);     // 30,720
  bf16* vT = hb;
  bf16* obuf = wqkvt;

  cast_h_kernel<<<5120, 256, 0, stream>>>(h, hb);
  bias_concat_kernel<<<30, 256, 0, stream>>>(q_b, k_b, v_b, bqkv);
  wtrans_kernel<<<dim3(80, 80, 4), dim3(32, 8), 0, stream>>>(q_w, k_w, v_w, dw, wqkvt, wdt);
  // QKV GEMM: M=2048, N=7680, K=2560 -> 8 x 30 = 240 tiles
  gemm256_kernel<true><<<240, 512, 0, stream>>>(hb, wqkvt, bqkv, qkv, Tq, NQKV, HIDq, 8);
  rope_kernel<<<4096, 256, 0, stream>>>(qkv, positions);
  vtrans_kernel<<<dim3(80, 32, 2), dim3(32, 8), 0, stream>>>(qkv, vT);
  attn_kernel<<<dim3(8, 32, 2), 256, 0, stream>>>(qkv, vT, obuf);
  gemm_bt_kernel<false><<<dim3(20, 16), 256, 0, stream>>>(obuf, wdt, db, d_out, Tq, HIDq, HIDq);
}

// Round 4
// 258.931 us; speedup vs baseline: 1.3283x; 1.1392x over previous
//
#include <hip/hip_runtime.h>
#include <hip/hip_bf16.h>

// Problem constants (PhiAttention: B=2,S=1024,HID=2560,H=32,D=80,ROT=32)
#define Bq 2
#define Sq 1024
#define Tq 2048
#define HIDq 2560
#define Hq 32
#define Dq 80
#define NQKV 7680   // 3*HID

typedef __bf16 bf16x8 __attribute__((ext_vector_type(8)));
typedef float f32x4 __attribute__((ext_vector_type(4)));
typedef unsigned short u16x8 __attribute__((ext_vector_type(8)));
using bf16 = __hip_bfloat16;

__device__ __forceinline__ void gload_lds16(const bf16* g, bf16* l) {
  __builtin_amdgcn_global_load_lds((const __attribute__((address_space(1))) void*)g,
                                   (__attribute__((address_space(3))) void*)l,
                                   16, 0, 0);
}

// ---------------- cast h (fp32 -> bf16) ----------------
__global__ __launch_bounds__(256) void cast_h_kernel(const float* __restrict__ h,
                                                     bf16* __restrict__ hb) {
  int i = (blockIdx.x * 256 + threadIdx.x) * 4;
  float4 v = *(const float4*)(h + i);
  bf16 tmp[4];
  tmp[0] = __float2bfloat16(v.x);
  tmp[1] = __float2bfloat16(v.y);
  tmp[2] = __float2bfloat16(v.z);
  tmp[3] = __float2bfloat16(v.w);
  *(ushort4*)(hb + i) = *(ushort4*)tmp;
}

// ---------------- concat qkv bias ----------------
__global__ __launch_bounds__(256) void bias_concat_kernel(const float* __restrict__ qb,
                                                          const float* __restrict__ kb,
                                                          const float* __restrict__ vb,
                                                          float* __restrict__ bqkv) {
  int i = blockIdx.x * 256 + threadIdx.x;
  if (i < HIDq) bqkv[i] = qb[i];
  else if (i < 2 * HIDq) bqkv[i] = kb[i - HIDq];
  else bqkv[i] = vb[i - 2 * HIDq];
}

// ---------------- transpose-cast weights: wt[n][k] = w[k][n], fp32->bf16 ----------------
__global__ __launch_bounds__(256) void wtrans_kernel(const float* __restrict__ qw,
                                                     const float* __restrict__ kw,
                                                     const float* __restrict__ vw,
                                                     const float* __restrict__ dw,
                                                     bf16* __restrict__ wqkvt,
                                                     bf16* __restrict__ wdt) {
  __shared__ float tile[32][33];
  const int z = blockIdx.z;
  const float* src = (z == 0) ? qw : (z == 1) ? kw : (z == 2) ? vw : dw;
  const int n0 = blockIdx.x * 32;  // src col  (dst row)
  const int k0 = blockIdx.y * 32;  // src row  (dst col)
  const int tx = threadIdx.x, ty = threadIdx.y;
#pragma unroll
  for (int r = 0; r < 4; r++)
    tile[ty + 8 * r][tx] = src[(size_t)(k0 + ty + 8 * r) * HIDq + n0 + tx];
  __syncthreads();
  bf16* dst = (z < 3) ? (wqkvt + (size_t)z * HIDq * HIDq) : wdt;
#pragma unroll
  for (int r = 0; r < 4; r++)
    dst[(size_t)(n0 + ty + 8 * r) * HIDq + k0 + tx] = __float2bfloat16(tile[tx][ty + 8 * r]);
}

// ================= pipelined GEMM (T1+T2+T3/T4+T5) =================
// C[M][N] = A[M][K] @ Bt[N][K]^T + bias.  8 waves (2Mx4N), per-wave C = (16*MFRAG) x 64.
// Tile = (32*MFRAG) x 256.  BK=32, 3-buffer LDS ring, counted vmcnt, raw s_barrier,
// XOR swizzle (pre-swizzled global source + swizzled ds_read — both-sides, rule 21).
template <int MFRAG, bool OUT_BF16>
__global__ __launch_bounds__(512, 2) void gemm256_kernel(const bf16* __restrict__ A,
                                                         const bf16* __restrict__ Bt,
                                                         const float* __restrict__ bias,
                                                         void* __restrict__ Cout,
                                                         int N, int K, int tMc) {
  constexpr int ACALLS = MFRAG / 4;        // global_load_lds calls for the A panel
  constexpr int APANEL = 8192 * ACALLS;    // bytes
  constexpr int BUFSZ = APANEL + 16384;
  __shared__ char smem[3 * BUFSZ];
  const int tid = threadIdx.x;
  const int lane = tid & 63;
  const int ln = lane & 15, lg = lane >> 4;
  const int wave = tid >> 6;
  const int wm = wave >> 2;   // 0..1
  const int wn = wave & 3;    // 0..3

  // XCD-aware bijective block swizzle (grids are multiples of 8)
  int bid = blockIdx.x;
  int swz = bid;
  int nwg = gridDim.x;
  if ((nwg & 7) == 0) { int cpx = nwg >> 3; swz = (bid & 7) * cpx + (bid >> 3); }
  const int m0 = (swz % tMc) * (32 * MFRAG);
  const int n0 = (swz / tMc) * 256;

  const int NT = K >> 5;  // K / 32

  f32x4 acc[MFRAG][4];
  const f32x4 zz = {0.f, 0.f, 0.f, 0.f};
#pragma unroll
  for (int i = 0; i < MFRAG; ++i)
#pragma unroll
    for (int j = 0; j < 4; ++j) acc[i][j] = zz;

  const int Rl0 = tid >> 2;        // stored-row within an 8KB call (0..127)
  const int slot = tid & 3;        // 16B slot within the 64B row
  const int wbase = (tid >> 6) * 1024;

  auto STAGE = [&](int t, int b) {
    const int k0 = t << 5;
    char* Ab = smem + b * BUFSZ;
    char* Bb = Ab + APANEL;
#pragma unroll
    for (int c = 0; c < ACALLS; ++c) {
      const int srow = c * 128 + Rl0;
      const int row = srow ^ ((srow >> 2) & 1);
      const int col8 = slot ^ (row & 3);
      gload_lds16(A + (size_t)(m0 + row) * K + k0 + col8 * 8,
                  (bf16*)(Ab + c * 8192 + wbase));
    }
#pragma unroll
    for (int c = 0; c < 2; ++c) {
      const int srow = c * 128 + Rl0;
      const int row = srow ^ ((srow >> 2) & 1);
      const int col8 = slot ^ (row & 3);
      gload_lds16(Bt + (size_t)(n0 + row) * K + k0 + col8 * 8,
                  (bf16*)(Bb + c * 8192 + wbase));
    }
  };

  auto FRAG = [&](const char* base, int row) -> bf16x8 {
    const unsigned off = ((unsigned)((row ^ ((row >> 2) & 1)) << 6)) |
                         (((unsigned)lg << 4) ^ ((unsigned)(row & 3) << 4));
    return *(const bf16x8*)(base + off);
  };

  auto WAIT_COUNTED = [&]() {
    if constexpr (ACALLS == 2) asm volatile("s_waitcnt vmcnt(4)" ::: "memory");
    else                       asm volatile("s_waitcnt vmcnt(3)" ::: "memory");
  };

  STAGE(0, 0);
  STAGE(1, 1);
  WAIT_COUNTED();
  __builtin_amdgcn_s_barrier();

  for (int t = 0; t < NT; ++t) {
    const int cb = t % 3;
    const char* Ab = smem + cb * BUFSZ;
    const char* Bb = Ab + APANEL;
    if (t + 2 < NT) STAGE(t + 2, (t + 2) % 3);

    bf16x8 bfr[4];
#pragma unroll
    for (int j = 0; j < 4; ++j) bfr[j] = FRAG(Bb, wn * 64 + j * 16 + ln);
#pragma unroll
    for (int ph = 0; ph < ACALLS; ++ph) {
      bf16x8 af[4];
#pragma unroll
      for (int i = 0; i < 4; ++i)
        af[i] = FRAG(Ab, wm * (16 * MFRAG) + (ph * 4 + i) * 16 + ln);
      __builtin_amdgcn_s_setprio(1);
#pragma unroll
      for (int i = 0; i < 4; ++i)
#pragma unroll
        for (int j = 0; j < 4; ++j)
          acc[ph * 4 + i][j] =
              __builtin_amdgcn_mfma_f32_16x16x32_bf16(af[i], bfr[j], acc[ph * 4 + i][j], 0, 0, 0);
      __builtin_amdgcn_s_setprio(0);
    }

    if (t + 2 < NT) WAIT_COUNTED();
    else            asm volatile("s_waitcnt vmcnt(0)" ::: "memory");
    __builtin_amdgcn_s_barrier();
  }

#pragma unroll
  for (int j = 0; j < 4; ++j) {
    const int col = n0 + wn * 64 + j * 16 + ln;
    const float bv = bias[col];
#pragma unroll
    for (int i = 0; i < MFRAG; ++i) {
      const int rowb = m0 + wm * (16 * MFRAG) + i * 16 + lg * 4;
#pragma unroll
      for (int r = 0; r < 4; ++r) {
        const float v = acc[i][j][r] + bv;
        if (OUT_BF16)
          ((bf16*)Cout)[(size_t)(rowb + r) * N + col] = __float2bfloat16(v);
        else
          ((float*)Cout)[(size_t)(rowb + r) * N + col] = v;
      }
    }
  }
}

// ---------------- RoPE on q and k (in-place, bf16) ----------------
__global__ __launch_bounds__(256) void rope_kernel(bf16* __restrict__ qkv,
                                                   const int* __restrict__ positions) {
  int tid = blockIdx.x * 256 + threadIdx.x;  // T*H*16
  int i = tid & 15;
  int h = (tid >> 4) & 31;
  int t = tid >> 9;
  float pos = (float)positions[t];
  // 10000^(-2i/32) = exp2(-i * log2(10000)/16)
  float inv = exp2f(-0.83048202372f * (float)i);
  float ang = pos * inv;
  float s, c;
  sincosf(ang, &s, &c);
  size_t base = (size_t)t * NQKV + h * Dq + i;
  {
    float x1 = __bfloat162float(qkv[base]);
    float x2 = __bfloat162float(qkv[base + 16]);
    qkv[base] = __float2bfloat16(x1 * c - x2 * s);
    qkv[base + 16] = __float2bfloat16(x2 * c + x1 * s);
  }
  base += HIDq;
  {
    float x1 = __bfloat162float(qkv[base]);
    float x2 = __bfloat162float(qkv[base + 16]);
    qkv[base] = __float2bfloat16(x1 * c - x2 * s);
    qkv[base + 16] = __float2bfloat16(x2 * c + x1 * s);
  }
}

// ---------------- V transpose: vT[b][hd][s] = v[b*S+s][hd] ----------------
__global__ __launch_bounds__(256) void vtrans_kernel(const bf16* __restrict__ qkv,
                                                     bf16* __restrict__ vT) {
  __shared__ bf16 tile[32][33];
  const int b = blockIdx.z;
  const int c0 = blockIdx.x * 32;  // hd
  const int s0 = blockIdx.y * 32;  // s
  const int tx = threadIdx.x, ty = threadIdx.y;
#pragma unroll
  for (int r = 0; r < 4; r++)
    tile[ty + 8 * r][tx] = qkv[(size_t)(b * Sq + s0 + ty + 8 * r) * NQKV + 2 * HIDq + c0 + tx];
  __syncthreads();
#pragma unroll
  for (int r = 0; r < 4; r++)
    vT[(size_t)b * HIDq * Sq + (size_t)(c0 + ty + 8 * r) * Sq + s0 + tx] = tile[tx][ty + 8 * r];
}

// ---------------- causal flash attention (balanced, QBLK=64, paired q-tiles) ----
// grid (8 pairs, 32 h, 2 b), 256 threads (4 waves x 16 q-rows).
// Block p handles q-tiles p and 15-p  -> exactly 17 KV-tile units per block.
// Q fragments live in registers; K/V staged in padded LDS (2-way conflicts only).
__global__ __launch_bounds__(256) void attn_kernel(const bf16* __restrict__ qkv,
                                                   const bf16* __restrict__ vT,
                                                   bf16* __restrict__ obuf) {
  const int p = blockIdx.x;
  const int h = blockIdx.y;
  const int b = blockIdx.z;
  __shared__ bf16 Ks[64][104];     // pad: 208B rows -> 2-way (free)
  __shared__ bf16 Vt[80][72];      // pad: 144B rows -> 2-way (free)
  __shared__ bf16 Ps[4][16][72];
  const int tid = threadIdx.x;
  const int wave = tid >> 6, lane = tid & 63;
  const int ln = lane & 15, lg = lane >> 4;
  const float scale = 0.1118033988749895f;  // 1/sqrt(80)
  const u16x8 zv = {0, 0, 0, 0, 0, 0, 0, 0};

#pragma unroll
  for (int qsel = 0; qsel < 2; ++qsel) {
    const int qt = qsel ? (15 - p) : p;

    // Q fragments -> registers (row = wave*16+ln, cols kc*32+lg*8; zero past 80)
    bf16x8 aq[3];
    {
      const size_t qbase = (size_t)(b * Sq + qt * 64 + wave * 16 + ln) * NQKV + h * Dq;
#pragma unroll
      for (int kc = 0; kc < 3; ++kc) {
        const int col = kc * 32 + lg * 8;
        u16x8 v = zv;
        if (col < 80) v = *(const u16x8*)(qkv + qbase + col);
        aq[kc] = *(bf16x8*)&v;
      }
    }

    float mstate[4], lstate[4];
    f32x4 oacc[5];
    const f32x4 zz = {0.f, 0.f, 0.f, 0.f};
#pragma unroll
    for (int r = 0; r < 4; ++r) { mstate[r] = -__builtin_inff(); lstate[r] = 0.f; }
#pragma unroll
    for (int n = 0; n < 5; ++n) oacc[n] = zz;

    for (int j = 0; j <= qt; ++j) {
      const int kv0 = j * 64;
      __syncthreads();  // previous iteration / q-tile done reading LDS
      // stage K tile (64 x 104, cols >=80 zero)
      for (int idx = tid; idx < 64 * 13; idx += 256) {
        int rr = idx / 13, c8 = idx % 13;
        u16x8 val = zv;
        if (c8 < 10)
          val = *(const u16x8*)(qkv + (size_t)(b * Sq + kv0 + rr) * NQKV + HIDq + h * Dq + c8 * 8);
        *(u16x8*)&Ks[rr][c8 * 8] = val;
      }
      // stage Vt tile (80 x 64 data; pad cols never read)
      for (int idx = tid; idx < 80 * 8; idx += 256) {
        int rr = idx >> 3, c8 = idx & 7;
        *(u16x8*)&Vt[rr][c8 * 8] =
            *(const u16x8*)(vT + (size_t)b * HIDq * Sq + (size_t)(h * Dq + rr) * Sq + kv0 + c8 * 8);
      }
      __syncthreads();

      // QK^T : 16 q-rows x 64 kv per wave
      f32x4 sacc[4];
#pragma unroll
      for (int n = 0; n < 4; ++n) sacc[n] = zz;
#pragma unroll
      for (int kc = 0; kc < 3; ++kc) {
        bf16x8 bk[4];
#pragma unroll
        for (int n = 0; n < 4; ++n) bk[n] = *(const bf16x8*)&Ks[n * 16 + ln][kc * 32 + lg * 8];
#pragma unroll
        for (int n = 0; n < 4; ++n)
          sacc[n] = __builtin_amdgcn_mfma_f32_16x16x32_bf16(aq[kc], bk[n], sacc[n], 0, 0, 0);
      }

      // online softmax; only the diagonal tile needs masking
      const bool diag = (j == qt);
#pragma unroll
      for (int r = 0; r < 4; ++r) {
        const int qloc = wave * 16 + lg * 4 + r;  // local q row within tile
        float v[4];
        float vmax = -__builtin_inff();
#pragma unroll
        for (int n = 0; n < 4; ++n) {
          float x = sacc[n][r] * scale;
          if (diag && (n * 16 + ln) > qloc) x = -__builtin_inff();
          v[n] = x;
          vmax = fmaxf(vmax, x);
        }
#pragma unroll
        for (int off = 8; off >= 1; off >>= 1) vmax = fmaxf(vmax, __shfl_xor(vmax, off, 64));
        const float mo = mstate[r];
        const float mn = fmaxf(mo, vmax);
        const float alpha = __expf(mo - mn);
        float psum = 0.f;
#pragma unroll
        for (int n = 0; n < 4; ++n) {
          const float pv = __expf(v[n] - mn);
          psum += pv;
          Ps[wave][lg * 4 + r][n * 16 + ln] = __float2bfloat16(pv);
        }
#pragma unroll
        for (int off = 8; off >= 1; off >>= 1) psum += __shfl_xor(psum, off, 64);
        lstate[r] = lstate[r] * alpha + psum;
        mstate[r] = mn;
#pragma unroll
        for (int n5 = 0; n5 < 5; ++n5) oacc[n5][r] *= alpha;
      }
      asm volatile("s_waitcnt lgkmcnt(0)" ::: "memory");
      __builtin_amdgcn_sched_barrier(0);

      // PV : oacc += P @ V
#pragma unroll
      for (int kc = 0; kc < 2; ++kc) {
        bf16x8 ap = *(const bf16x8*)&Ps[wave][ln][kc * 32 + lg * 8];
        bf16x8 bv[5];
#pragma unroll
        for (int n = 0; n < 5; ++n) bv[n] = *(const bf16x8*)&Vt[n * 16 + ln][kc * 32 + lg * 8];
#pragma unroll
        for (int n = 0; n < 5; ++n)
          oacc[n] = __builtin_amdgcn_mfma_f32_16x16x32_bf16(ap, bv[n], oacc[n], 0, 0, 0);
      }
    }

    // epilogue
#pragma unroll
    for (int r = 0; r < 4; ++r) {
      const float inv = 1.0f / lstate[r];
      const size_t rowbase =
          (size_t)(b * Sq + qt * 64 + wave * 16 + lg * 4 + r) * HIDq + h * Dq;
#pragma unroll
      for (int n5 = 0; n5 < 5; ++n5)
        obuf[rowbase + n5 * 16 + ln] = __float2bfloat16(oacc[n5][r] * inv);
    }
  }
}

// ---------------- launch ----------------
extern "C" void kernel_launch(void* const* d_in, const int* in_sizes, int n_in,
                              void* d_out, int out_size, void* d_ws, size_t ws_size,
                              hipStream_t stream) {
  const float* h = (const float*)d_in[0];
  const float* q_w = (const float*)d_in[3];
  const float* q_b = (const float*)d_in[4];
  const float* k_w = (const float*)d_in[5];
  const float* k_b = (const float*)d_in[6];
  const float* v_w = (const float*)d_in[7];
  const float* v_b = (const float*)d_in[8];
  const float* dw = (const float*)d_in[9];
  const float* db = (const float*)d_in[10];
  const int* positions = (const int*)d_in[11];

  if (ws_size < 94402560ull) return;
  char* ws = (char*)d_ws;
  bf16* hb = (bf16*)(ws);                    // 10,485,760
  bf16* wqkvt = (bf16*)(ws + 10485760);      // 39,321,600
  bf16* wdt = (bf16*)(ws + 49807360);        // 13,107,200
  bf16* qkv = (bf16*)(ws + 62914560);        // 31,457,280
  float* bqkv = (float*)(ws + 94371840);     // 30,720
  bf16* vT = hb;       // h dead after QKV gemm
  bf16* obuf = wqkvt;  // qkv weights dead after QKV gemm

  cast_h_kernel<<<5120, 256, 0, stream>>>(h, hb);
  bias_concat_kernel<<<30, 256, 0, stream>>>(q_b, k_b, v_b, bqkv);
  wtrans_kernel<<<dim3(80, 80, 4), dim3(32, 8), 0, stream>>>(q_w, k_w, v_w, dw, wqkvt, wdt);
  // QKV GEMM: 256x256 tiles -> 8 x 30 = 240 blocks
  gemm256_kernel<8, true><<<240, 512, 0, stream>>>(hb, wqkvt, bqkv, qkv, NQKV, HIDq, 8);
  rope_kernel<<<4096, 256, 0, stream>>>(qkv, positions);
  vtrans_kernel<<<dim3(80, 32, 2), dim3(32, 8), 0, stream>>>(qkv, vT);
  attn_kernel<<<dim3(8, 32, 2), 256, 0, stream>>>(qkv, vT, obuf);
  // dense GEMM: 128x256 tiles -> 16 x 10 = 160 blocks
  gemm256_kernel<4, false><<<160, 512, 0, stream>>>(obuf, wdt, db, d_out, HIDq, HIDq, 16);
}